// Round 4
// baseline (19.078 us; speedup 1.0000x reference)
//
#include <hip/hip_runtime.h>

// Dihedral2Coord — quaternion affine prefix-scan, one molecule per wave.
//
// final[m] = P_{m-3}(pos0[m]); P_k = B_0∘...∘B_k where B_k is the LOCAL-frame
// step rotation (dihedrals are rigid-invariant so phi_k comes from pos0 only).
// State = unit quaternion + translation (7 floats). Lane k of a wave handles
// steps 2k,2k+1: local pre-compose, 6-round shfl_up scan, one exclusive
// shuffle for the even prefix. Tail atoms transformed by P_127 (broadcast from
// lane 63), with their float4s prefetched into registers BEFORE the scan so
// HBM latency hides under scan compute.

#define NK 128
#define NM 512
#define NMOL 4096
#define TPB 256
#define MPB 4     // one molecule per wave

struct Aff { float qw, qx, qy, qz, tx, ty, tz; };

__device__ __forceinline__ void qrot(float qw, float qx, float qy, float qz,
                                     float vx, float vy, float vz,
                                     float& ox, float& oy, float& oz) {
    // v' = v + 2*qv×(qv×v + qw*v)
    const float ux = qy*vz - qz*vy + qw*vx;
    const float uy = qz*vx - qx*vz + qw*vy;
    const float uz = qx*vy - qy*vx + qw*vz;
    ox = vx + 2.f*(qy*uz - qz*uy);
    oy = vy + 2.f*(qz*ux - qx*uz);
    oz = vz + 2.f*(qx*uy - qy*ux);
}

// (Q∘P)(x) = Q(P(x)):  q = qQ⊗qP,  t = R(qQ)·tP + tQ
__device__ __forceinline__ Aff aff_compose(const Aff& Q, const Aff& P) {
    Aff r;
    r.qw = Q.qw*P.qw - Q.qx*P.qx - Q.qy*P.qy - Q.qz*P.qz;
    r.qx = Q.qw*P.qx + Q.qx*P.qw + Q.qy*P.qz - Q.qz*P.qy;
    r.qy = Q.qw*P.qy - Q.qx*P.qz + Q.qy*P.qw + Q.qz*P.qx;
    r.qz = Q.qw*P.qz + Q.qx*P.qy - Q.qy*P.qx + Q.qz*P.qw;
    float rx, ry, rz;
    qrot(Q.qw, Q.qx, Q.qy, Q.qz, P.tx, P.ty, P.tz, rx, ry, rz);
    r.tx = rx + Q.tx; r.ty = ry + Q.ty; r.tz = rz + Q.tz;
    return r;
}

__device__ __forceinline__ void qnorm(Aff& a) {
    const float r = rsqrtf(a.qw*a.qw + a.qx*a.qx + a.qy*a.qy + a.qz*a.qz);
    a.qw *= r; a.qx *= r; a.qy *= r; a.qz *= r;
}

// B for one step: atoms I,J,K,L at a[0..11], extra angle th.
__device__ __forceinline__ Aff build_B(const float* a, float th) {
    const float ijx=a[3]-a[0], ijy=a[4]-a[1],  ijz=a[5]-a[2];
    const float jkx=a[6]-a[3], jky=a[7]-a[4],  jkz=a[8]-a[5];
    const float klx=a[9]-a[6], kly=a[10]-a[7], klz=a[11]-a[8];
    const float n1x=ijy*jkz-ijz*jky, n1y=ijz*jkx-ijx*jkz, n1z=ijx*jky-ijy*jkx;
    const float n2x=jky*klz-jkz*kly, n2y=jkz*klx-jkx*klz, n2z=jkx*kly-jky*klx;
    const float mx =n1y*jkz-n1z*jky, my =n1z*jkx-n1x*jkz, mz =n1x*jky-n1y*jkx;
    const float dmn=mx*n2x+my*n2y+mz*n2z;
    const float dnn=n1x*n2x+n1y*n2y+n1z*n2z;
    const float Lm =mx*mx+my*my+mz*mz;
    const float L1 =n1x*n1x+n1y*n1y+n1z*n1z;
    const float L2 =n2x*n2x+n2y*n2y+n2z*n2z;
    // (cphi,sphi) == (cos,sin)(atan2(sin_arg,cos_arg)) up to ulps
    float sphi = dmn*rsqrtf(Lm*L2);
    float cphi = dnn*rsqrtf(L1*L2);
    const float rn = rsqrtf(sphi*sphi + cphi*cphi);
    sphi *= rn; cphi *= rn;
    float sth, cth; sincosf(th, &sth, &cth);
    const float c = cth*cphi - sth*sphi;   // cos(theta+phi)
    const float s = sth*cphi + cth*sphi;   // sin(theta+phi)
    const float Ljk = jkx*jkx + jky*jky + jkz*jkz;
    const float inva = rsqrtf(fmaxf(Ljk, 1e-24f));
    const float ax = jkx*inva, ay = jky*inva, az = jkz*inva;
    // half-angle (branchless, stable; q and -q equivalent)
    const float hc = sqrtf(fmaxf(0.f, 0.5f*(1.f + c)));
    const float hs = copysignf(sqrtf(fmaxf(0.f, 0.5f*(1.f - c))), s);
    Aff b;
    b.qw = hc; b.qx = hs*ax; b.qy = hs*ay; b.qz = hs*az;
    float rx, ry, rz;
    qrot(b.qw, b.qx, b.qy, b.qz, a[3], a[4], a[5], rx, ry, rz);
    b.tx = a[3] - rx; b.ty = a[4] - ry; b.tz = a[5] - rz;  // t = J - R·J
    return b;
}

#define SHFL_AFF_UP(D, S, off)                                           \
    D.qw = __shfl_up(S.qw, off, 64); D.qx = __shfl_up(S.qx, off, 64);    \
    D.qy = __shfl_up(S.qy, off, 64); D.qz = __shfl_up(S.qz, off, 64);    \
    D.tx = __shfl_up(S.tx, off, 64); D.ty = __shfl_up(S.ty, off, 64);    \
    D.tz = __shfl_up(S.tz, off, 64);

__global__ __launch_bounds__(TPB, 4) void dihedral_quat_scan_kernel(
    const float* __restrict__ theta,  // (NMOL, NK)
    const float* __restrict__ pos0,   // (NMOL, NM, 3)
    float* __restrict__ out)          // (NMOL, NM, 3)
{
    const int tid  = threadIdx.x;
    const int lane = tid & 63;
    const int wid  = tid >> 6;
    const int mol  = blockIdx.x * MPB + wid;
    const float4* __restrict__ pb4 = (const float4*)(pos0 + (size_t)mol * (NM*3));
    float4*       __restrict__ ob4 = (float4*)(out  + (size_t)mol * (NM*3));

    __shared__ float sA[MPB][400];   // pos0 atoms 0..131 (396 used)
    __shared__ float sO[MPB][400];   // final atoms 0..131

    // stage head (99 float4) + theta (float2/lane)
    float4* sA4 = (float4*)sA[wid];
    for (int i = lane; i < 99; i += 64) sA4[i] = pb4[i];
    const float2 th2 = ((const float2*)(theta + (size_t)mol * NK))[lane];

    // prefetch BOTH tail tasks into registers (overlaps scan compute)
    const int t0 = lane, t1 = 64 + lane;
    const bool has2 = (t1 < 95);
    float4 Ta0, Ta1, Ta2, Tb0, Tb1, Tb2;
    { const int b = 99 + 3*t0; Ta0 = pb4[b]; Ta1 = pb4[b+1]; Ta2 = pb4[b+2]; }
    if (has2) { const int b = 99 + 3*t1; Tb0 = pb4[b]; Tb1 = pb4[b+1]; Tb2 = pb4[b+2]; }

    __syncthreads();

    // lane k: atoms 2k..2k+4 (15 floats)
    float A[15];
    const float* ap = &sA[wid][lane * 6];
    #pragma unroll
    for (int i = 0; i < 15; ++i) A[i] = ap[i];

    Aff Bev = build_B(&A[0], th2.x);     // B_{2k}
    Aff Bod = build_B(&A[3], th2.y);     // B_{2k+1}
    Aff S   = aff_compose(Bev, Bod);     // C_k = B_{2k}∘B_{2k+1}

    // inclusive wave scan: S -> C_0∘...∘C_k = P_{2k+1}
    #pragma unroll
    for (int off = 1; off < 64; off <<= 1) {
        Aff Q; SHFL_AFF_UP(Q, S, off);
        if (lane >= off) S = aff_compose(Q, S);
    }
    // exclusive prefix (identity at lane 0), P_{2k} = E∘B_{2k}
    Aff E; SHFL_AFF_UP(E, S, 1);
    if (lane == 0) { E.qw = 1.f; E.qx = E.qy = E.qz = 0.f; E.tx = E.ty = E.tz = 0.f; }
    Aff Pe = aff_compose(E, Bev);
    qnorm(Pe); qnorm(S);

    // emit atoms 2k+3 (via P_{2k}) and 2k+4 (via P_{2k+1}) into LDS
    {
        float ox, oy, oz;
        float* op = &sO[wid][lane * 6 + 9];
        qrot(Pe.qw, Pe.qx, Pe.qy, Pe.qz, A[9], A[10], A[11], ox, oy, oz);
        op[0] = ox + Pe.tx; op[1] = oy + Pe.ty; op[2] = oz + Pe.tz;
        qrot(S.qw, S.qx, S.qy, S.qz, A[12], A[13], A[14], ox, oy, oz);
        op[3] = ox + S.tx;  op[4] = oy + S.ty;  op[5] = oz + S.tz;
    }
    if (lane < 9) sO[wid][lane] = sA[wid][lane];   // atoms 0..2 never move
    if (lane == 63) {                              // atom 131 = P_127(pos0[131])
        float ox, oy, oz;
        qrot(S.qw, S.qx, S.qy, S.qz, sA[wid][393], sA[wid][394], sA[wid][395], ox, oy, oz);
        sO[wid][393] = ox + S.tx; sO[wid][394] = oy + S.ty; sO[wid][395] = oz + S.tz;
    }

    // broadcast F = P_127 from lane 63, build its matrix once per lane
    Aff F;
    F.qw = __shfl(S.qw, 63, 64); F.qx = __shfl(S.qx, 63, 64);
    F.qy = __shfl(S.qy, 63, 64); F.qz = __shfl(S.qz, 63, 64);
    F.tx = __shfl(S.tx, 63, 64); F.ty = __shfl(S.ty, 63, 64);
    F.tz = __shfl(S.tz, 63, 64);
    const float f00 = 1.f - 2.f*(F.qy*F.qy + F.qz*F.qz);
    const float f01 = 2.f*(F.qx*F.qy - F.qw*F.qz);
    const float f02 = 2.f*(F.qx*F.qz + F.qw*F.qy);
    const float f10 = 2.f*(F.qx*F.qy + F.qw*F.qz);
    const float f11 = 1.f - 2.f*(F.qx*F.qx + F.qz*F.qz);
    const float f12 = 2.f*(F.qy*F.qz - F.qw*F.qx);
    const float f20 = 2.f*(F.qx*F.qz - F.qw*F.qy);
    const float f21 = 2.f*(F.qy*F.qz + F.qw*F.qx);
    const float f22 = 1.f - 2.f*(F.qx*F.qx + F.qy*F.qy);

    __syncthreads();

    // store head (99 float4 from LDS)
    const float4* sO4 = (const float4*)sO[wid];
    for (int i = lane; i < 99; i += 64) ob4[i] = sO4[i];

    // tail: task t = 4 atoms = 3 float4 in/out, data already in registers
    #define TAIL_EMIT(b, va, vb, vc)                                          \
    do {                                                                      \
        const float x0=va.x, y0=va.y, z0=va.z;                                \
        const float x1=va.w, y1=vb.x, z1=vb.y;                                \
        const float x2=vb.z, y2=vb.w, z2=vc.x;                                \
        const float x3=vc.y, y3=vc.z, z3=vc.w;                                \
        float4 o0, o1, o2;                                                    \
        o0.x = f00*x0+f01*y0+f02*z0+F.tx; o0.y = f10*x0+f11*y0+f12*z0+F.ty;   \
        o0.z = f20*x0+f21*y0+f22*z0+F.tz; o0.w = f00*x1+f01*y1+f02*z1+F.tx;   \
        o1.x = f10*x1+f11*y1+f12*z1+F.ty; o1.y = f20*x1+f21*y1+f22*z1+F.tz;   \
        o1.z = f00*x2+f01*y2+f02*z2+F.tx; o1.w = f10*x2+f11*y2+f12*z2+F.ty;   \
        o2.x = f20*x2+f21*y2+f22*z2+F.tz; o2.y = f00*x3+f01*y3+f02*z3+F.tx;   \
        o2.z = f10*x3+f11*y3+f12*z3+F.ty; o2.w = f20*x3+f21*y3+f22*z3+F.tz;   \
        ob4[(b)] = o0; ob4[(b)+1] = o1; ob4[(b)+2] = o2;                      \
    } while (0)

    TAIL_EMIT(99 + 3*t0, Ta0, Ta1, Ta2);
    if (has2) TAIL_EMIT(99 + 3*t1, Tb0, Tb1, Tb2);
    #undef TAIL_EMIT
}

extern "C" void kernel_launch(void* const* d_in, const int* in_sizes, int n_in,
                              void* d_out, int out_size, void* d_ws, size_t ws_size,
                              hipStream_t stream) {
    const float* theta = (const float*)d_in[0];  // input (N,K) fp32
    const float* pos0  = (const float*)d_in[1];  // pos0 (N,M,3) fp32
    float* out = (float*)d_out;                  // (N,M,3) fp32
    dihedral_quat_scan_kernel<<<NMOL / MPB, TPB, 0, stream>>>(theta, pos0, out);
}